// Round 2
// baseline (1526.421 us; speedup 1.0000x reference)
//
#include <hip/hip_runtime.h>

#define NU 100000
#define NI 100000
#define NE 500000
#define HD 128

using bf16x8 = __attribute__((ext_vector_type(8))) __bf16;
using f32x4  = __attribute__((ext_vector_type(4))) float;

// ---------------- src-degree histograms (3 arrays; dst degrees come from CSR cnt) ----
__global__ __launch_bounds__(256) void src_count(
    const int* __restrict__ s0, const int* __restrict__ s1,
    const int* __restrict__ s2, float* __restrict__ deg)
{
    long long t = (long long)blockIdx.x * 256 + threadIdx.x;
    if (t >= 3LL * NE) return;
    int a = (int)(t / NE);
    int e = (int)(t - (long long)a * NE);
    const int* p = (a == 0) ? s0 : (a == 1) ? s1 : s2;
    atomicAdd(&deg[a * 200000 + p[e]], 1.0f);
}

__global__ __launch_bounds__(256) void deg_finalize(float* __restrict__ deg)
{
    int t = blockIdx.x * 256 + threadIdx.x;
    if (t < 600000) deg[t] = rsqrtf(fmaxf(deg[t], 1.0f));
}

__global__ __launch_bounds__(256) void rs_from_cnt(const int* __restrict__ cnt,
                                                   float* __restrict__ rs, int n)
{
    int t = blockIdx.x * 256 + threadIdx.x;
    if (t < n) rs[t] = rsqrtf(fmaxf((float)cnt[t], 1.0f));
}

// ---------------- CSR build ----------------
__global__ __launch_bounds__(256) void count_dst(const int* __restrict__ dst,
                                                 int* __restrict__ cnt)
{
    int e = blockIdx.x * 256 + threadIdx.x;
    if (e < NE) atomicAdd(&cnt[dst[e]], 1);
}

__global__ __launch_bounds__(256) void scan_block(const int* __restrict__ cnt, int n,
                                                  int* __restrict__ rp,
                                                  int* __restrict__ bsum)
{
    __shared__ int s[256];
    int gid = blockIdx.x * 256 + threadIdx.x;
    int v = (gid < n) ? cnt[gid] : 0;
    s[threadIdx.x] = v;
    __syncthreads();
#pragma unroll
    for (int off = 1; off < 256; off <<= 1) {
        int t = (threadIdx.x >= off) ? s[threadIdx.x - off] : 0;
        __syncthreads();
        s[threadIdx.x] += t;
        __syncthreads();
    }
    if (gid < n) rp[gid] = s[threadIdx.x] - v;   // exclusive
    if (threadIdx.x == 255) bsum[blockIdx.x] = s[255];
}

__global__ __launch_bounds__(512) void scan_bsums(int* __restrict__ bsum, int nb)
{
    __shared__ int s[512];
    int v = (threadIdx.x < nb) ? bsum[threadIdx.x] : 0;
    s[threadIdx.x] = v;
    __syncthreads();
#pragma unroll
    for (int off = 1; off < 512; off <<= 1) {
        int t = (threadIdx.x >= off) ? s[threadIdx.x - off] : 0;
        __syncthreads();
        s[threadIdx.x] += t;
        __syncthreads();
    }
    if (threadIdx.x < nb) bsum[threadIdx.x] = s[threadIdx.x] - v;
    if (threadIdx.x == 0) bsum[nb] = s[nb - 1];  // total
}

__global__ __launch_bounds__(256) void scan_add(int* __restrict__ rp,
                                                const int* __restrict__ bsum,
                                                int n, int nb)
{
    int gid = blockIdx.x * 256 + threadIdx.x;
    if (gid < n) rp[gid] += bsum[blockIdx.x];
    if (gid == 0) rp[n] = bsum[nb];
}

__global__ __launch_bounds__(256) void csr_fill(const int* __restrict__ src,
                                                const int* __restrict__ dst,
                                                const int* __restrict__ rp,
                                                int* __restrict__ cursor,
                                                int* __restrict__ eidx)
{
    int e = blockIdx.x * 256 + threadIdx.x;
    if (e >= NE) return;
    int d = dst[e];
    int pos = rp[d] + atomicAdd(&cursor[d], 1);
    eidx[pos] = src[e];
}

// ---------------- CSR gather: m[d] = sum_{e in csr[d]} x[src_e] * rs[src_e] --------
// unroll-4 for memory-level parallelism (serial dep-chain was the bottleneck)
__global__ __launch_bounds__(256) void gather_scaled(
    const float* __restrict__ x, const float* __restrict__ rs,
    const int* __restrict__ rp, const int* __restrict__ eidx,
    float* __restrict__ m, int n)
{
    int row = blockIdx.x * 8 + (threadIdx.x >> 5);
    int c = (threadIdx.x & 31) * 4;
    if (row >= n) return;
    int beg = rp[row], end = rp[row + 1];
    float ax = 0.f, ay = 0.f, az = 0.f, aw = 0.f;
    int p = beg;
    for (; p + 4 <= end; p += 4) {
        int s0 = eidx[p], s1 = eidx[p + 1], s2 = eidx[p + 2], s3 = eidx[p + 3];
        float r0 = rs[s0], r1 = rs[s1], r2 = rs[s2], r3 = rs[s3];
        float4 v0 = *(const float4*)(x + (long long)s0 * HD + c);
        float4 v1 = *(const float4*)(x + (long long)s1 * HD + c);
        float4 v2 = *(const float4*)(x + (long long)s2 * HD + c);
        float4 v3 = *(const float4*)(x + (long long)s3 * HD + c);
        ax = fmaf(v0.x, r0, ax); ay = fmaf(v0.y, r0, ay);
        az = fmaf(v0.z, r0, az); aw = fmaf(v0.w, r0, aw);
        ax = fmaf(v1.x, r1, ax); ay = fmaf(v1.y, r1, ay);
        az = fmaf(v1.z, r1, az); aw = fmaf(v1.w, r1, aw);
        ax = fmaf(v2.x, r2, ax); ay = fmaf(v2.y, r2, ay);
        az = fmaf(v2.z, r2, az); aw = fmaf(v2.w, r2, aw);
        ax = fmaf(v3.x, r3, ax); ay = fmaf(v3.y, r3, ay);
        az = fmaf(v3.z, r3, az); aw = fmaf(v3.w, r3, aw);
    }
    for (; p < end; ++p) {
        int s = eidx[p];
        float sc = rs[s];
        float4 v = *(const float4*)(x + (long long)s * HD + c);
        ax = fmaf(v.x, sc, ax); ay = fmaf(v.y, sc, ay);
        az = fmaf(v.z, sc, az); aw = fmaf(v.w, sc, aw);
    }
    *(float4*)(m + (long long)row * HD + c) = make_float4(ax, ay, az, aw);
}

// ---------------- W pre-pass: fp32 [K x 128] -> transposed bf16 hi/lo [128 x Kpad] ----
__global__ __launch_bounds__(256) void convert_w(
    const float* __restrict__ W, int K, int Kpad,
    __bf16* __restrict__ Wh, __bf16* __restrict__ Wl)
{
    int t = blockIdx.x * 256 + threadIdx.x;
    if (t >= 128 * Kpad) return;
    int k = t >> 7;
    int n = t & 127;
    float x = (k < K) ? W[k * 128 + n] : 0.f;
    __bf16 h = (__bf16)x;
    float r = x - (float)h;
    Wh[n * Kpad + k] = h;
    Wl[n * Kpad + k] = (__bf16)r;
}

// ---------------- K=128 specialized GEMM: C[M x 128] = A[M x 128] @ W ----------------
// W hi/lo fragments in registers (loaded once); A streamed in 32-row chunks through
// double-buffered LDS (stride 136 = 2-way-free banks); one barrier per chunk;
// global loads for chunk c+1 issued before MFMA phase of chunk c (latency hidden).
#define CPB 3
__global__ __launch_bounds__(256) void gemm_k128(
    const float* __restrict__ A, int M,
    const __bf16* __restrict__ Wh, const __bf16* __restrict__ Wl,
    const float* __restrict__ bias,
    const float* __restrict__ out_scale,
    int do_relu, int do_accum,
    float* __restrict__ C)
{
    __shared__ __bf16 sAh[2][32 * 136];
    __shared__ __bf16 sAl[2][32 * 136];

    const int tid  = threadIdx.x;
    const int lane = tid & 63;
    const int wv   = tid >> 6;    // wave -> 32-col slice
    const int lr   = lane & 15;
    const int lq   = lane >> 4;

    // ---- B fragments for this wave's 32 columns, all of K=128, hi+lo (64 VGPRs) ----
    bf16x8 bh[2][4], bl[2][4];
#pragma unroll
    for (int j = 0; j < 2; ++j)
#pragma unroll
        for (int kc = 0; kc < 4; ++kc) {
            int col = wv * 32 + j * 16 + lr;
            int k = kc * 32 + lq * 8;
            bh[j][kc] = *(const bf16x8*)(Wh + col * 128 + k);
            bl[j][kc] = *(const bf16x8*)(Wl + col * 128 + k);
        }

    const int nch = (M + 31) >> 5;
    const int c0 = blockIdx.x * CPB;
    const int cend = (c0 + CPB < nch) ? c0 + CPB : nch;

    const int srow  = tid >> 3;         // 0..31
    const int skoff = (tid & 7) << 4;   // 0..112

    float4 pre[4];

#define LOADREG(c)                                                              \
    {                                                                           \
        int row = (c) * 32 + srow;                                              \
        if (row < M) {                                                          \
            const float* p = A + (long long)row * 128 + skoff;                  \
            pre[0] = *(const float4*)(p);                                       \
            pre[1] = *(const float4*)(p + 4);                                   \
            pre[2] = *(const float4*)(p + 8);                                   \
            pre[3] = *(const float4*)(p + 12);                                  \
        } else {                                                                \
            pre[0] = pre[1] = pre[2] = pre[3] = make_float4(0.f, 0.f, 0.f, 0.f);\
        }                                                                       \
    }

#define CVTWRITE(buf)                                                           \
    {                                                                           \
        float fv[16] = {pre[0].x, pre[0].y, pre[0].z, pre[0].w,                 \
                        pre[1].x, pre[1].y, pre[1].z, pre[1].w,                 \
                        pre[2].x, pre[2].y, pre[2].z, pre[2].w,                 \
                        pre[3].x, pre[3].y, pre[3].z, pre[3].w};                \
        bf16x8 h0, h1, l0, l1;                                                  \
        _Pragma("unroll")                                                       \
        for (int t = 0; t < 8; ++t) {                                           \
            __bf16 h = (__bf16)fv[t];                                           \
            h0[t] = h; l0[t] = (__bf16)(fv[t] - (float)h);                      \
        }                                                                       \
        _Pragma("unroll")                                                       \
        for (int t = 0; t < 8; ++t) {                                           \
            __bf16 h = (__bf16)fv[8 + t];                                       \
            h1[t] = h; l1[t] = (__bf16)(fv[8 + t] - (float)h);                  \
        }                                                                       \
        *(bf16x8*)(&sAh[buf][srow * 136 + skoff])     = h0;                     \
        *(bf16x8*)(&sAh[buf][srow * 136 + skoff + 8]) = h1;                     \
        *(bf16x8*)(&sAl[buf][srow * 136 + skoff])     = l0;                     \
        *(bf16x8*)(&sAl[buf][srow * 136 + skoff + 8]) = l1;                     \
    }

    LOADREG(c0);
    CVTWRITE(0);
    __syncthreads();

    for (int c = c0; c < cend; ++c) {
        const int buf = (c - c0) & 1;
        const bool more = (c + 1 < cend);
        if (more) LOADREG(c + 1);   // issue next-chunk loads; latency hides under MFMA

        f32x4 acc[2][2];
#pragma unroll
        for (int i = 0; i < 2; ++i)
#pragma unroll
            for (int j = 0; j < 2; ++j)
#pragma unroll
                for (int t = 0; t < 4; ++t) acc[i][j][t] = 0.f;

#pragma unroll
        for (int i = 0; i < 2; ++i) {
#pragma unroll
            for (int kc = 0; kc < 4; ++kc) {
                bf16x8 ah = *(const bf16x8*)(&sAh[buf][(i * 16 + lr) * 136 + kc * 32 + lq * 8]);
                bf16x8 al = *(const bf16x8*)(&sAl[buf][(i * 16 + lr) * 136 + kc * 32 + lq * 8]);
#pragma unroll
                for (int j = 0; j < 2; ++j) {
                    acc[i][j] = __builtin_amdgcn_mfma_f32_16x16x32_bf16(ah, bh[j][kc], acc[i][j], 0, 0, 0);
                    acc[i][j] = __builtin_amdgcn_mfma_f32_16x16x32_bf16(ah, bl[j][kc], acc[i][j], 0, 0, 0);
                    acc[i][j] = __builtin_amdgcn_mfma_f32_16x16x32_bf16(al, bh[j][kc], acc[i][j], 0, 0, 0);
                }
            }
        }

        // epilogue for chunk c
#pragma unroll
        for (int j = 0; j < 2; ++j) {
            int col = wv * 32 + j * 16 + lr;
            float bv = bias ? bias[col] : 0.f;
#pragma unroll
            for (int i = 0; i < 2; ++i) {
                int r0 = c * 32 + i * 16 + lq * 4;
#pragma unroll
                for (int t = 0; t < 4; ++t) {
                    int row = r0 + t;
                    if (row < M) {
                        float s = out_scale ? out_scale[row] : 1.f;
                        float v = acc[i][j][t] * s + bv;
                        if (do_relu) v = fmaxf(v, 0.f);
                        float* cp = C + (long long)row * 128 + col;
                        if (do_accum) v += *cp;
                        *cp = v;
                    }
                }
            }
        }

        if (more) CVTWRITE(buf ^ 1);   // write NEXT buffer (disjoint from current reads)
        __syncthreads();               // single barrier per chunk
    }
#undef LOADREG
#undef CVTWRITE
}

// ---------------- generic-K MFMA GEMM (kept for the two embed GEMMs) ----------------
__global__ __launch_bounds__(256) void gemm128_mfma(
    const float* __restrict__ A, int K, int Kpad, int M,
    const __bf16* __restrict__ Wh, const __bf16* __restrict__ Wl,
    const float* __restrict__ bias,
    const float* __restrict__ out_scale,
    int do_relu, int do_accum,
    float* __restrict__ C)
{
    __shared__ __bf16 sAh[64 * 40];
    __shared__ __bf16 sAl[64 * 40];
    __shared__ __bf16 sWh[128 * 40];
    __shared__ __bf16 sWl[128 * 40];

    const int tid  = threadIdx.x;
    const int row0 = blockIdx.x * 64;
    const int lane = tid & 63;
    const int wv   = tid >> 6;
    const int lr   = lane & 15;
    const int lq   = lane >> 4;

    f32x4 acc[4][2];
#pragma unroll
    for (int i = 0; i < 4; ++i)
#pragma unroll
        for (int j = 0; j < 2; ++j)
#pragma unroll
            for (int t = 0; t < 4; ++t) acc[i][j][t] = 0.f;

    const int arow  = tid >> 2;
    const int akoff = (tid & 3) << 3;
    const int wcol  = tid >> 1;
    const int wkoff = (tid & 1) << 4;

    const int nk = Kpad >> 5;
    for (int kc = 0; kc < nk; ++kc) {
        const int k0 = kc << 5;
        {
            int row = row0 + arow;
            int k = k0 + akoff;
            float f[8];
            if (row < M && k + 7 < K) {
                float4 v0 = *(const float4*)(A + (long long)row * K + k);
                float4 v1 = *(const float4*)(A + (long long)row * K + k + 4);
                f[0] = v0.x; f[1] = v0.y; f[2] = v0.z; f[3] = v0.w;
                f[4] = v1.x; f[5] = v1.y; f[6] = v1.z; f[7] = v1.w;
            } else {
#pragma unroll
                for (int t = 0; t < 8; ++t)
                    f[t] = (row < M && k + t < K) ? A[(long long)row * K + k + t] : 0.f;
            }
            bf16x8 h8, l8;
#pragma unroll
            for (int t = 0; t < 8; ++t) {
                __bf16 h = (__bf16)f[t];
                h8[t] = h;
                l8[t] = (__bf16)(f[t] - (float)h);
            }
            *(bf16x8*)(&sAh[arow * 40 + akoff]) = h8;
            *(bf16x8*)(&sAl[arow * 40 + akoff]) = l8;
        }
        {
            const __bf16* ph = Wh + (long long)wcol * Kpad + k0 + wkoff;
            const __bf16* pl = Wl + (long long)wcol * Kpad + k0 + wkoff;
            bf16x8 w0 = *(const bf16x8*)(ph);
            bf16x8 w1 = *(const bf16x8*)(ph + 8);
            bf16x8 x0 = *(const bf16x8*)(pl);
            bf16x8 x1 = *(const bf16x8*)(pl + 8);
            *(bf16x8*)(&sWh[wcol * 40 + wkoff])     = w0;
            *(bf16x8*)(&sWh[wcol * 40 + wkoff + 8]) = w1;
            *(bf16x8*)(&sWl[wcol * 40 + wkoff])     = x0;
            *(bf16x8*)(&sWl[wcol * 40 + wkoff + 8]) = x1;
        }
        __syncthreads();
        bf16x8 bh[2], bl[2];
#pragma unroll
        for (int j = 0; j < 2; ++j) {
            int c = wv * 32 + j * 16 + lr;
            bh[j] = *(const bf16x8*)(&sWh[c * 40 + lq * 8]);
            bl[j] = *(const bf16x8*)(&sWl[c * 40 + lq * 8]);
        }
#pragma unroll
        for (int i = 0; i < 4; ++i) {
            bf16x8 ah = *(const bf16x8*)(&sAh[(i * 16 + lr) * 40 + lq * 8]);
            bf16x8 al = *(const bf16x8*)(&sAl[(i * 16 + lr) * 40 + lq * 8]);
#pragma unroll
            for (int j = 0; j < 2; ++j) {
                acc[i][j] = __builtin_amdgcn_mfma_f32_16x16x32_bf16(ah, bh[j], acc[i][j], 0, 0, 0);
                acc[i][j] = __builtin_amdgcn_mfma_f32_16x16x32_bf16(ah, bl[j], acc[i][j], 0, 0, 0);
                acc[i][j] = __builtin_amdgcn_mfma_f32_16x16x32_bf16(al, bh[j], acc[i][j], 0, 0, 0);
            }
        }
        __syncthreads();
    }

#pragma unroll
    for (int j = 0; j < 2; ++j) {
        int col = wv * 32 + j * 16 + lr;
        float bv = bias ? bias[col] : 0.f;
#pragma unroll
        for (int i = 0; i < 4; ++i) {
            int r0 = row0 + i * 16 + lq * 4;
#pragma unroll
            for (int t = 0; t < 4; ++t) {
                int row = r0 + t;
                if (row < M) {
                    float s = out_scale ? out_scale[row] : 1.f;
                    float v = acc[i][j][t] * s + bv;
                    if (do_relu) v = fmaxf(v, 0.f);
                    float* cp = C + (long long)row * 128 + col;
                    if (do_accum) v += *cp;
                    *cp = v;
                }
            }
        }
    }
}

static inline void build_csr(const int* src, const int* dst, int n_dst,
                             int* cnt, int* rp, int* cursor, int* eidx,
                             int* bsum, float* rs_in, hipStream_t stream)
{
    const int nb = (n_dst + 255) / 256;
    hipMemsetAsync(cnt, 0, n_dst * sizeof(int), stream);
    count_dst<<<(NE + 255) / 256, 256, 0, stream>>>(dst, cnt);
    rs_from_cnt<<<nb, 256, 0, stream>>>(cnt, rs_in, n_dst);
    scan_block<<<nb, 256, 0, stream>>>(cnt, n_dst, rp, bsum);
    scan_bsums<<<1, 512, 0, stream>>>(bsum, nb);
    scan_add<<<nb, 256, 0, stream>>>(rp, bsum, n_dst, nb);
    hipMemsetAsync(cursor, 0, n_dst * sizeof(int), stream);
    csr_fill<<<(NE + 255) / 256, 256, 0, stream>>>(src, dst, rp, cursor, eidx);
}

extern "C" void kernel_launch(void* const* d_in, const int* in_sizes, int n_in,
                              void* d_out, int out_size, void* d_ws, size_t ws_size,
                              hipStream_t stream)
{
    const float* feat_user = (const float*)d_in[0];
    const float* feat_item = (const float*)d_in[1];
    const int* src_uu = (const int*)d_in[2];
    const int* dst_uu = (const int*)d_in[3];
    const int* src_ui = (const int*)d_in[4];
    const int* dst_ui = (const int*)d_in[5];
    const int* src_iu = (const int*)d_in[6];
    const int* dst_iu = (const int*)d_in[7];
    const float* We_u = (const float*)d_in[8];
    const float* be_u = (const float*)d_in[9];
    const float* We_i = (const float*)d_in[10];
    const float* be_i = (const float*)d_in[11];

    float* hu = (float*)d_out;                 // [NU x 128]
    float* hi = hu + (size_t)NU * HD;          // [NI x 128]

    float* ws   = (float*)d_ws;
    float* m_uu = ws;                          // [NU x 128] dst=user
    float* m_ui = m_uu + (size_t)NU * HD;      // [NI x 128] dst=item
    float* m_iu = m_ui + (size_t)NI * HD;      // [NU x 128] dst=user
    float* deg  = m_iu + (size_t)NU * HD;      // 6 x 100000
    float* rs_out_uu = deg + 0;
    float* rs_in_uu  = deg + 100000;
    float* rs_out_ui = deg + 200000;
    float* rs_in_ui  = deg + 300000;
    float* rs_out_iu = deg + 400000;
    float* rs_in_iu  = deg + 500000;

    int* ib = (int*)(deg + 600000);
    int* rp_uu   = ib;                 ib += 100001;
    int* rp_ui   = ib;                 ib += 100001;
    int* rp_iu   = ib;                 ib += 100001;
    int* ei_uu   = ib;                 ib += NE;
    int* ei_ui   = ib;                 ib += NE;
    int* ei_iu   = ib;                 ib += NE;
    int* cnt     = ib;                 ib += 100000;
    int* cursor  = ib;                 ib += 100000;
    int* bsum    = ib;                 ib += 1024;

    // bf16 hi/lo transposed weight buffers (~884 KB)
    uintptr_t wp = ((uintptr_t)ib + 63) & ~(uintptr_t)63;
    __bf16* wtbuf = (__bf16*)wp;
    __bf16* eu_h = wtbuf;                       // 128*256
    __bf16* eu_l = eu_h + 128 * 256;
    __bf16* ei_h = eu_l + 128 * 256;            // 128*320
    __bf16* ei_l = ei_h + 128 * 320;
    __bf16* lw   = ei_l + 128 * 320;            // 9 x (hi,lo) of 128*128

    // weight conversion pre-pass (tiny)
    convert_w<<<(128 * 256 + 255) / 256, 256, 0, stream>>>(We_u, 256, 256, eu_h, eu_l);
    convert_w<<<(128 * 320 + 255) / 256, 256, 0, stream>>>(We_i, 300, 320, ei_h, ei_l);
    for (int l = 0; l < 3; ++l)
        for (int e = 0; e < 3; ++e) {
            const float* W = (const float*)d_in[12 + 6 * l + 2 * e];
            __bf16* h = lw + (size_t)(l * 3 + e) * 2 * 16384;
            convert_w<<<64, 256, 0, stream>>>(W, 128, 128, h, h + 16384);
        }

    // src-degree histograms only (dst degrees derived from CSR counts)
    hipMemsetAsync(deg, 0, 600000 * sizeof(float), stream);
    src_count<<<(3 * NE + 255) / 256, 256, 0, stream>>>(src_uu, src_ui, src_iu, deg);
    deg_finalize<<<(600000 + 255) / 256, 256, 0, stream>>>(deg);

    // CSR (dst-major) per etype; each also produces rs_in_* from its histogram
    build_csr(src_uu, dst_uu, NU, cnt, rp_uu, cursor, ei_uu, bsum, rs_in_uu, stream);
    build_csr(src_ui, dst_ui, NI, cnt, rp_ui, cursor, ei_ui, bsum, rs_in_ui, stream);
    build_csr(src_iu, dst_iu, NU, cnt, rp_iu, cursor, ei_iu, bsum, rs_in_iu, stream);

    // HeteroLinear embed (generic-K kernel)
    gemm128_mfma<<<(NU + 63) / 64, 256, 0, stream>>>(feat_user, 256, 256, NU,
                                                     eu_h, eu_l, be_u, nullptr, 0, 0, hu);
    gemm128_mfma<<<(NI + 63) / 64, 256, 0, stream>>>(feat_item, 300, 320, NI,
                                                     ei_h, ei_l, be_i, nullptr, 0, 0, hi);

    const int gat_blocks_u = (NU + 7) / 8;
    const int gat_blocks_i = (NI + 7) / 8;
    const int nch_u = (NU + 31) / 32;
    const int nch_i = (NI + 31) / 32;
    const int gk_blocks_u = (nch_u + CPB - 1) / CPB;
    const int gk_blocks_i = (nch_i + CPB - 1) / CPB;
    for (int l = 0; l < 3; ++l) {
        const float* b_uu = (const float*)d_in[12 + 6 * l + 1];
        const float* b_ui = (const float*)d_in[12 + 6 * l + 3];
        const float* b_iu = (const float*)d_in[12 + 6 * l + 5];
        __bf16* wh_uu = lw + (size_t)(l * 3 + 0) * 2 * 16384;
        __bf16* wh_ui = lw + (size_t)(l * 3 + 1) * 2 * 16384;
        __bf16* wh_iu = lw + (size_t)(l * 3 + 2) * 2 * 16384;
        const int relu = (l < 2) ? 1 : 0;

        // aggregate-first: m[d] = sum over in-edges of x[src]*rsqrt(deg_out[src])
        gather_scaled<<<gat_blocks_u, 256, 0, stream>>>(hu, rs_out_uu, rp_uu, ei_uu, m_uu, NU);
        gather_scaled<<<gat_blocks_i, 256, 0, stream>>>(hu, rs_out_ui, rp_ui, ei_ui, m_ui, NI);
        gather_scaled<<<gat_blocks_u, 256, 0, stream>>>(hi, rs_out_iu, rp_iu, ei_iu, m_iu, NU);
        // GEMM with fused epilogue: relu((m @ W) * rsqrt(deg_in) + b), summed per dst ntype
        gemm_k128<<<gk_blocks_u, 256, 0, stream>>>(m_uu, NU,
            wh_uu, wh_uu + 16384, b_uu, rs_in_uu, relu, 0, hu);
        gemm_k128<<<gk_blocks_u, 256, 0, stream>>>(m_iu, NU,
            wh_iu, wh_iu + 16384, b_iu, rs_in_iu, relu, 1, hu);
        gemm_k128<<<gk_blocks_i, 256, 0, stream>>>(m_ui, NI,
            wh_ui, wh_ui + 16384, b_ui, rs_in_ui, relu, 0, hi);
    }
}

// Round 3
// 1418.274 us; speedup vs baseline: 1.0763x; 1.0763x over previous
//
#include <hip/hip_runtime.h>

#define NU 100000
#define NI 100000
#define NE 500000
#define HD 128

using bf16x8 = __attribute__((ext_vector_type(8))) __bf16;
using f32x4  = __attribute__((ext_vector_type(4))) float;

// ---------------- src-degree histograms (3 arrays; dst degrees come from CSR cnt) ----
__global__ __launch_bounds__(256) void src_count(
    const int* __restrict__ s0, const int* __restrict__ s1,
    const int* __restrict__ s2, float* __restrict__ deg)
{
    long long t = (long long)blockIdx.x * 256 + threadIdx.x;
    if (t >= 3LL * NE) return;
    int a = (int)(t / NE);
    int e = (int)(t - (long long)a * NE);
    const int* p = (a == 0) ? s0 : (a == 1) ? s1 : s2;
    atomicAdd(&deg[a * 200000 + p[e]], 1.0f);
}

__global__ __launch_bounds__(256) void deg_finalize(float* __restrict__ deg)
{
    int t = blockIdx.x * 256 + threadIdx.x;
    if (t < 600000) deg[t] = rsqrtf(fmaxf(deg[t], 1.0f));
}

__global__ __launch_bounds__(256) void rs_from_cnt(const int* __restrict__ cnt,
                                                   float* __restrict__ rs, int n)
{
    int t = blockIdx.x * 256 + threadIdx.x;
    if (t < n) rs[t] = rsqrtf(fmaxf((float)cnt[t], 1.0f));
}

// ---------------- CSR build ----------------
__global__ __launch_bounds__(256) void count_dst(const int* __restrict__ dst,
                                                 int* __restrict__ cnt)
{
    int e = blockIdx.x * 256 + threadIdx.x;
    if (e < NE) atomicAdd(&cnt[dst[e]], 1);
}

__global__ __launch_bounds__(256) void scan_block(const int* __restrict__ cnt, int n,
                                                  int* __restrict__ rp,
                                                  int* __restrict__ bsum)
{
    __shared__ int s[256];
    int gid = blockIdx.x * 256 + threadIdx.x;
    int v = (gid < n) ? cnt[gid] : 0;
    s[threadIdx.x] = v;
    __syncthreads();
#pragma unroll
    for (int off = 1; off < 256; off <<= 1) {
        int t = (threadIdx.x >= off) ? s[threadIdx.x - off] : 0;
        __syncthreads();
        s[threadIdx.x] += t;
        __syncthreads();
    }
    if (gid < n) rp[gid] = s[threadIdx.x] - v;   // exclusive
    if (threadIdx.x == 255) bsum[blockIdx.x] = s[255];
}

__global__ __launch_bounds__(512) void scan_bsums(int* __restrict__ bsum, int nb)
{
    __shared__ int s[512];
    int v = (threadIdx.x < nb) ? bsum[threadIdx.x] : 0;
    s[threadIdx.x] = v;
    __syncthreads();
#pragma unroll
    for (int off = 1; off < 512; off <<= 1) {
        int t = (threadIdx.x >= off) ? s[threadIdx.x - off] : 0;
        __syncthreads();
        s[threadIdx.x] += t;
        __syncthreads();
    }
    if (threadIdx.x < nb) bsum[threadIdx.x] = s[threadIdx.x] - v;
    if (threadIdx.x == 0) bsum[nb] = s[nb - 1];  // total
}

__global__ __launch_bounds__(256) void scan_add(int* __restrict__ rp,
                                                const int* __restrict__ bsum,
                                                int n, int nb)
{
    int gid = blockIdx.x * 256 + threadIdx.x;
    if (gid < n) rp[gid] += bsum[blockIdx.x];
    if (gid == 0) rp[n] = bsum[nb];
}

__global__ __launch_bounds__(256) void csr_fill(const int* __restrict__ src,
                                                const int* __restrict__ dst,
                                                const int* __restrict__ rp,
                                                int* __restrict__ cursor,
                                                int* __restrict__ eidx)
{
    int e = blockIdx.x * 256 + threadIdx.x;
    if (e >= NE) return;
    int d = dst[e];
    int pos = rp[d] + atomicAdd(&cursor[d], 1);
    eidx[pos] = src[e];
}

// ---------------- W pre-pass: fp32 [K x 128] -> transposed bf16 hi/lo [128 x Kpad] ----
__global__ __launch_bounds__(256) void convert_w(
    const float* __restrict__ W, int K, int Kpad,
    __bf16* __restrict__ Wh, __bf16* __restrict__ Wl)
{
    int t = blockIdx.x * 256 + threadIdx.x;
    if (t >= 128 * Kpad) return;
    int k = t >> 7;
    int n = t & 127;
    float x = (k < K) ? W[k * 128 + n] : 0.f;
    __bf16 h = (__bf16)x;
    float r = x - (float)h;
    Wh[n * Kpad + k] = h;
    Wl[n * Kpad + k] = (__bf16)r;
}

// ---------------- fused layer kernel helpers ----------------

// gather one 32-row tile: 16 groups x 16 lanes; group g owns rows g*2, g*2+1;
// lane gl owns cols gl*8..gl*8+7. fp32 accumulate -> bf16 hi/lo split -> LDS.
__device__ __forceinline__ void gather_stage(
    const float* __restrict__ X, const int* __restrict__ rp,
    const int* __restrict__ ei, const float* __restrict__ rs,
    int r0, int M, int g, int gl, __bf16* sAh, __bf16* sAl)
{
#pragma unroll
    for (int t = 0; t < 2; ++t) {
        const int lrow = g * 2 + t;
        const int row = r0 + lrow;
        float a[8] = {0.f, 0.f, 0.f, 0.f, 0.f, 0.f, 0.f, 0.f};
        if (row < M) {
            int beg = rp[row], end = rp[row + 1];
            int p = beg;
            for (; p + 2 <= end; p += 2) {        // unroll-2: 2 edges in flight
                int s0 = ei[p], s1 = ei[p + 1];
                float w0 = rs[s0], w1 = rs[s1];
                const float* x0 = X + (long long)s0 * HD + gl * 8;
                const float* x1 = X + (long long)s1 * HD + gl * 8;
                float4 u0 = *(const float4*)x0;
                float4 u1 = *(const float4*)(x0 + 4);
                float4 v0 = *(const float4*)x1;
                float4 v1 = *(const float4*)(x1 + 4);
                a[0] = fmaf(u0.x, w0, a[0]); a[1] = fmaf(u0.y, w0, a[1]);
                a[2] = fmaf(u0.z, w0, a[2]); a[3] = fmaf(u0.w, w0, a[3]);
                a[4] = fmaf(u1.x, w0, a[4]); a[5] = fmaf(u1.y, w0, a[5]);
                a[6] = fmaf(u1.z, w0, a[6]); a[7] = fmaf(u1.w, w0, a[7]);
                a[0] = fmaf(v0.x, w1, a[0]); a[1] = fmaf(v0.y, w1, a[1]);
                a[2] = fmaf(v0.z, w1, a[2]); a[3] = fmaf(v0.w, w1, a[3]);
                a[4] = fmaf(v1.x, w1, a[4]); a[5] = fmaf(v1.y, w1, a[5]);
                a[6] = fmaf(v1.z, w1, a[6]); a[7] = fmaf(v1.w, w1, a[7]);
            }
            if (p < end) {
                int s0 = ei[p];
                float w0 = rs[s0];
                const float* x0 = X + (long long)s0 * HD + gl * 8;
                float4 u0 = *(const float4*)x0;
                float4 u1 = *(const float4*)(x0 + 4);
                a[0] = fmaf(u0.x, w0, a[0]); a[1] = fmaf(u0.y, w0, a[1]);
                a[2] = fmaf(u0.z, w0, a[2]); a[3] = fmaf(u0.w, w0, a[3]);
                a[4] = fmaf(u1.x, w0, a[4]); a[5] = fmaf(u1.y, w0, a[5]);
                a[6] = fmaf(u1.z, w0, a[6]); a[7] = fmaf(u1.w, w0, a[7]);
            }
        }
        bf16x8 h8, l8;
#pragma unroll
        for (int q = 0; q < 8; ++q) {
            __bf16 hq = (__bf16)a[q];
            h8[q] = hq;
            l8[q] = (__bf16)(a[q] - (float)hq);
        }
        *(bf16x8*)(&sAh[lrow * 136 + gl * 8]) = h8;
        *(bf16x8*)(&sAl[lrow * 136 + gl * 8]) = l8;
    }
}

// W fragments for this wave's 32 cols, all K=128, hi+lo (64 VGPRs); L2-resident source.
__device__ __forceinline__ void load_wfrags(const __bf16* __restrict__ W,
                                            int wv, int lr, int lq,
                                            bf16x8 bh[2][4], bf16x8 bl[2][4])
{
    const __bf16* Wlo = W + 16384;
#pragma unroll
    for (int j = 0; j < 2; ++j)
#pragma unroll
        for (int kc = 0; kc < 4; ++kc) {
            int col = wv * 32 + j * 16 + lr;
            int k = kc * 32 + lq * 8;
            bh[j][kc] = *(const bf16x8*)(W + col * 128 + k);
            bl[j][kc] = *(const bf16x8*)(Wlo + col * 128 + k);
        }
}

__device__ __forceinline__ void mfma_tile(const __bf16* sAh, const __bf16* sAl,
                                          int lr, int lq,
                                          const bf16x8 bh[2][4], const bf16x8 bl[2][4],
                                          f32x4 acc[2][2])
{
#pragma unroll
    for (int i = 0; i < 2; ++i)
#pragma unroll
        for (int kc = 0; kc < 4; ++kc) {
            bf16x8 ah = *(const bf16x8*)(&sAh[(i * 16 + lr) * 136 + kc * 32 + lq * 8]);
            bf16x8 al = *(const bf16x8*)(&sAl[(i * 16 + lr) * 136 + kc * 32 + lq * 8]);
#pragma unroll
            for (int j = 0; j < 2; ++j) {
                acc[i][j] = __builtin_amdgcn_mfma_f32_16x16x32_bf16(ah, bh[j][kc], acc[i][j], 0, 0, 0);
                acc[i][j] = __builtin_amdgcn_mfma_f32_16x16x32_bf16(ah, bl[j][kc], acc[i][j], 0, 0, 0);
                acc[i][j] = __builtin_amdgcn_mfma_f32_16x16x32_bf16(al, bh[j][kc], acc[i][j], 0, 0, 0);
            }
        }
}

// ---------------- fused layer: gather + split-bf16 GEMM + (optional) 2nd edge set ----
// C[row] = relu(gatherA@Wa * rsa_d + ba) [+ relu(gatherB@Wb * rsb_d + bb)]
// One 32-row output tile per block; hu written exactly once (no accum RMW).
__global__ __launch_bounds__(256) void layer_fused(
    const float* __restrict__ Xa, const float* __restrict__ Xb,   // Xb==null -> single set
    const int* __restrict__ rp_a, const int* __restrict__ ei_a,
    const float* __restrict__ rsa_s, const float* __restrict__ rsa_d,
    const __bf16* __restrict__ Wa, const float* __restrict__ ba,
    const int* __restrict__ rp_b, const int* __restrict__ ei_b,
    const float* __restrict__ rsb_s, const float* __restrict__ rsb_d,
    const __bf16* __restrict__ Wb, const float* __restrict__ bb,
    int do_relu, int M, float* __restrict__ C)
{
    __shared__ __bf16 sAh[32 * 136];
    __shared__ __bf16 sAl[32 * 136];

    const int tid  = threadIdx.x;
    const int lane = tid & 63;
    const int wv   = tid >> 6;       // wave -> 32-col slice
    const int lr   = lane & 15;
    const int lq   = lane >> 4;
    const int g    = tid >> 4;       // gather group 0..15
    const int gl   = tid & 15;       // lane in group
    const int r0   = blockIdx.x * 32;
    const bool dual = (Xb != nullptr);

    bf16x8 bh[2][4], bl[2][4];
    f32x4 accA[2][2], accB[2][2];
#pragma unroll
    for (int i = 0; i < 2; ++i)
#pragma unroll
        for (int j = 0; j < 2; ++j)
#pragma unroll
            for (int t = 0; t < 4; ++t) { accA[i][j][t] = 0.f; accB[i][j][t] = 0.f; }

    // ---- set A: W-frag loads (L2) overlap the gather's dependent-load chain ----
    load_wfrags(Wa, wv, lr, lq, bh, bl);
    gather_stage(Xa, rp_a, ei_a, rsa_s, r0, M, g, gl, sAh, sAl);
    __syncthreads();                       // tile staged
    mfma_tile(sAh, sAl, lr, lq, bh, bl, accA);

    if (dual) {
        __syncthreads();                   // all reads of tile A complete
        load_wfrags(Wb, wv, lr, lq, bh, bl);   // reuses frag regs after MFMA-A
        gather_stage(Xb, rp_b, ei_b, rsb_s, r0, M, g, gl, sAh, sAl);
        __syncthreads();
        mfma_tile(sAh, sAl, lr, lq, bh, bl, accB);
    }

    // ---- epilogue: per-set scale+bias+relu, sum, single write ----
#pragma unroll
    for (int j = 0; j < 2; ++j) {
        const int col = wv * 32 + j * 16 + lr;
        const float bva = ba[col];
        const float bvb = dual ? bb[col] : 0.f;
#pragma unroll
        for (int i = 0; i < 2; ++i) {
            const int rbase = r0 + i * 16 + lq * 4;
#pragma unroll
            for (int t = 0; t < 4; ++t) {
                const int row = rbase + t;
                if (row < M) {
                    float ya = accA[i][j][t] * rsa_d[row] + bva;
                    if (do_relu) ya = fmaxf(ya, 0.f);
                    float out = ya;
                    if (dual) {
                        float yb = accB[i][j][t] * rsb_d[row] + bvb;
                        if (do_relu) yb = fmaxf(yb, 0.f);
                        out += yb;
                    }
                    C[(long long)row * HD + col] = out;
                }
            }
        }
    }
}

// ---------------- generic-K MFMA GEMM (embeds only; unchanged control) ----------------
__global__ __launch_bounds__(256) void gemm128_mfma(
    const float* __restrict__ A, int K, int Kpad, int M,
    const __bf16* __restrict__ Wh, const __bf16* __restrict__ Wl,
    const float* __restrict__ bias,
    float* __restrict__ C)
{
    __shared__ __bf16 sAh[64 * 40];
    __shared__ __bf16 sAl[64 * 40];
    __shared__ __bf16 sWh[128 * 40];
    __shared__ __bf16 sWl[128 * 40];

    const int tid  = threadIdx.x;
    const int row0 = blockIdx.x * 64;
    const int lane = tid & 63;
    const int wv   = tid >> 6;
    const int lr   = lane & 15;
    const int lq   = lane >> 4;

    f32x4 acc[4][2];
#pragma unroll
    for (int i = 0; i < 4; ++i)
#pragma unroll
        for (int j = 0; j < 2; ++j)
#pragma unroll
            for (int t = 0; t < 4; ++t) acc[i][j][t] = 0.f;

    const int arow  = tid >> 2;
    const int akoff = (tid & 3) << 3;
    const int wcol  = tid >> 1;
    const int wkoff = (tid & 1) << 4;

    const int nk = Kpad >> 5;
    for (int kc = 0; kc < nk; ++kc) {
        const int k0 = kc << 5;
        {
            int row = row0 + arow;
            int k = k0 + akoff;
            float f[8];
            if (row < M && k + 7 < K) {
                float4 v0 = *(const float4*)(A + (long long)row * K + k);
                float4 v1 = *(const float4*)(A + (long long)row * K + k + 4);
                f[0] = v0.x; f[1] = v0.y; f[2] = v0.z; f[3] = v0.w;
                f[4] = v1.x; f[5] = v1.y; f[6] = v1.z; f[7] = v1.w;
            } else {
#pragma unroll
                for (int t = 0; t < 8; ++t)
                    f[t] = (row < M && k + t < K) ? A[(long long)row * K + k + t] : 0.f;
            }
            bf16x8 h8, l8;
#pragma unroll
            for (int t = 0; t < 8; ++t) {
                __bf16 h = (__bf16)f[t];
                h8[t] = h;
                l8[t] = (__bf16)(f[t] - (float)h);
            }
            *(bf16x8*)(&sAh[arow * 40 + akoff]) = h8;
            *(bf16x8*)(&sAl[arow * 40 + akoff]) = l8;
        }
        {
            const __bf16* ph = Wh + (long long)wcol * Kpad + k0 + wkoff;
            const __bf16* pl = Wl + (long long)wcol * Kpad + k0 + wkoff;
            bf16x8 w0 = *(const bf16x8*)(ph);
            bf16x8 w1 = *(const bf16x8*)(ph + 8);
            bf16x8 x0 = *(const bf16x8*)(pl);
            bf16x8 x1 = *(const bf16x8*)(pl + 8);
            *(bf16x8*)(&sWh[wcol * 40 + wkoff])     = w0;
            *(bf16x8*)(&sWh[wcol * 40 + wkoff + 8]) = w1;
            *(bf16x8*)(&sWl[wcol * 40 + wkoff])     = x0;
            *(bf16x8*)(&sWl[wcol * 40 + wkoff + 8]) = x1;
        }
        __syncthreads();
        bf16x8 bh[2], bl[2];
#pragma unroll
        for (int j = 0; j < 2; ++j) {
            int c = wv * 32 + j * 16 + lr;
            bh[j] = *(const bf16x8*)(&sWh[c * 40 + lq * 8]);
            bl[j] = *(const bf16x8*)(&sWl[c * 40 + lq * 8]);
        }
#pragma unroll
        for (int i = 0; i < 4; ++i) {
            bf16x8 ah = *(const bf16x8*)(&sAh[(i * 16 + lr) * 40 + lq * 8]);
            bf16x8 al = *(const bf16x8*)(&sAl[(i * 16 + lr) * 40 + lq * 8]);
#pragma unroll
            for (int j = 0; j < 2; ++j) {
                acc[i][j] = __builtin_amdgcn_mfma_f32_16x16x32_bf16(ah, bh[j], acc[i][j], 0, 0, 0);
                acc[i][j] = __builtin_amdgcn_mfma_f32_16x16x32_bf16(ah, bl[j], acc[i][j], 0, 0, 0);
                acc[i][j] = __builtin_amdgcn_mfma_f32_16x16x32_bf16(al, bh[j], acc[i][j], 0, 0, 0);
            }
        }
        __syncthreads();
    }

#pragma unroll
    for (int j = 0; j < 2; ++j) {
        int col = wv * 32 + j * 16 + lr;
        float bv = bias ? bias[col] : 0.f;
#pragma unroll
        for (int i = 0; i < 4; ++i) {
            int r0 = row0 + i * 16 + lq * 4;
#pragma unroll
            for (int t = 0; t < 4; ++t) {
                int row = r0 + t;
                if (row < M) {
                    float v = acc[i][j][t] + bv;
                    C[(long long)row * 128 + col] = v;
                }
            }
        }
    }
}

static inline void build_csr(const int* src, const int* dst, int n_dst,
                             int* cnt, int* rp, int* cursor, int* eidx,
                             int* bsum, float* rs_in, hipStream_t stream)
{
    const int nb = (n_dst + 255) / 256;
    hipMemsetAsync(cnt, 0, n_dst * sizeof(int), stream);
    count_dst<<<(NE + 255) / 256, 256, 0, stream>>>(dst, cnt);
    rs_from_cnt<<<nb, 256, 0, stream>>>(cnt, rs_in, n_dst);
    scan_block<<<nb, 256, 0, stream>>>(cnt, n_dst, rp, bsum);
    scan_bsums<<<1, 512, 0, stream>>>(bsum, nb);
    scan_add<<<nb, 256, 0, stream>>>(rp, bsum, n_dst, nb);
    hipMemsetAsync(cursor, 0, n_dst * sizeof(int), stream);
    csr_fill<<<(NE + 255) / 256, 256, 0, stream>>>(src, dst, rp, cursor, eidx);
}

extern "C" void kernel_launch(void* const* d_in, const int* in_sizes, int n_in,
                              void* d_out, int out_size, void* d_ws, size_t ws_size,
                              hipStream_t stream)
{
    const float* feat_user = (const float*)d_in[0];
    const float* feat_item = (const float*)d_in[1];
    const int* src_uu = (const int*)d_in[2];
    const int* dst_uu = (const int*)d_in[3];
    const int* src_ui = (const int*)d_in[4];
    const int* dst_ui = (const int*)d_in[5];
    const int* src_iu = (const int*)d_in[6];
    const int* dst_iu = (const int*)d_in[7];
    const float* We_u = (const float*)d_in[8];
    const float* be_u = (const float*)d_in[9];
    const float* We_i = (const float*)d_in[10];
    const float* be_i = (const float*)d_in[11];

    float* hu = (float*)d_out;                 // [NU x 128] final user out
    float* hi = hu + (size_t)NU * HD;          // [NI x 128] final item out

    float* ws = (float*)d_ws;
    float* wu = ws;                            // ping-pong state (user)
    float* wi = wu + (size_t)NU * HD;          // ping-pong state (item)
    float* deg = wi + (size_t)NI * HD;         // 6 x 100000
    float* rs_out_uu = deg + 0;
    float* rs_in_uu  = deg + 100000;
    float* rs_out_ui = deg + 200000;
    float* rs_in_ui  = deg + 300000;
    float* rs_out_iu = deg + 400000;
    float* rs_in_iu  = deg + 500000;

    int* ib = (int*)(deg + 600000);
    int* rp_uu   = ib;                 ib += 100001;
    int* rp_ui   = ib;                 ib += 100001;
    int* rp_iu   = ib;                 ib += 100001;
    int* ei_uu   = ib;                 ib += NE;
    int* ei_ui   = ib;                 ib += NE;
    int* ei_iu   = ib;                 ib += NE;
    int* cnt     = ib;                 ib += 100000;
    int* cursor  = ib;                 ib += 100000;
    int* bsum    = ib;                 ib += 1024;

    // bf16 hi/lo transposed weight buffers (~884 KB)
    uintptr_t wp = ((uintptr_t)ib + 63) & ~(uintptr_t)63;
    __bf16* wtbuf = (__bf16*)wp;
    __bf16* eu_h = wtbuf;                       // 128*256
    __bf16* eu_l = eu_h + 128 * 256;
    __bf16* ei_h = eu_l + 128 * 256;            // 128*320
    __bf16* ei_l = ei_h + 128 * 320;
    __bf16* lw   = ei_l + 128 * 320;            // 9 x (hi,lo) of 128*128

    // weight conversion pre-pass (tiny)
    convert_w<<<(128 * 256 + 255) / 256, 256, 0, stream>>>(We_u, 256, 256, eu_h, eu_l);
    convert_w<<<(128 * 320 + 255) / 256, 256, 0, stream>>>(We_i, 300, 320, ei_h, ei_l);
    for (int l = 0; l < 3; ++l)
        for (int e = 0; e < 3; ++e) {
            const float* W = (const float*)d_in[12 + 6 * l + 2 * e];
            __bf16* h = lw + (size_t)(l * 3 + e) * 2 * 16384;
            convert_w<<<64, 256, 0, stream>>>(W, 128, 128, h, h + 16384);
        }

    // src-degree histograms only (dst degrees derived from CSR counts)
    hipMemsetAsync(deg, 0, 600000 * sizeof(float), stream);
    src_count<<<(3 * NE + 255) / 256, 256, 0, stream>>>(src_uu, src_ui, src_iu, deg);
    deg_finalize<<<(600000 + 255) / 256, 256, 0, stream>>>(deg);

    // CSR (dst-major) per etype; each also produces rs_in_* from its histogram
    build_csr(src_uu, dst_uu, NU, cnt, rp_uu, cursor, ei_uu, bsum, rs_in_uu, stream);
    build_csr(src_ui, dst_ui, NI, cnt, rp_ui, cursor, ei_ui, bsum, rs_in_ui, stream);
    build_csr(src_iu, dst_iu, NU, cnt, rp_iu, cursor, ei_iu, bsum, rs_in_iu, stream);

    // HeteroLinear embed -> ping-pong buffers (ws)
    gemm128_mfma<<<(NU + 63) / 64, 256, 0, stream>>>(feat_user, 256, 256, NU,
                                                     eu_h, eu_l, be_u, wu);
    gemm128_mfma<<<(NI + 63) / 64, 256, 0, stream>>>(feat_item, 300, 320, NI,
                                                     ei_h, ei_l, be_i, wi);

    // layers: ping-pong ws <-> d_out; layer 2 lands in d_out
    const float* cu = wu; const float* ci = wi;
    float* nu = hu; float* ni = hi;
    const int blocks_u = (NU + 31) / 32;
    const int blocks_i = (NI + 31) / 32;
    for (int l = 0; l < 3; ++l) {
        const float* b_uu = (const float*)d_in[12 + 6 * l + 1];
        const float* b_ui = (const float*)d_in[12 + 6 * l + 3];
        const float* b_iu = (const float*)d_in[12 + 6 * l + 5];
        const __bf16* Wuu = lw + (size_t)(l * 3 + 0) * 2 * 16384;
        const __bf16* Wui = lw + (size_t)(l * 3 + 1) * 2 * 16384;
        const __bf16* Wiu = lw + (size_t)(l * 3 + 2) * 2 * 16384;
        const int relu = (l < 2) ? 1 : 0;

        // user dst: relu(gather_uu(cu)@Wuu) + relu(gather_iu(ci)@Wiu), single write
        layer_fused<<<blocks_u, 256, 0, stream>>>(
            cu, ci,
            rp_uu, ei_uu, rs_out_uu, rs_in_uu, Wuu, b_uu,
            rp_iu, ei_iu, rs_out_iu, rs_in_iu, Wiu, b_iu,
            relu, NU, nu);
        // item dst: relu(gather_ui(cu)@Wui), single write
        layer_fused<<<blocks_i, 256, 0, stream>>>(
            cu, nullptr,
            rp_ui, ei_ui, rs_out_ui, rs_in_ui, Wui, b_ui,
            rp_ui, ei_ui, rs_out_ui, rs_in_ui, Wui, b_ui,
            relu, NI, ni);

        // swap ping-pong
        const float* tu = cu; const float* ti = ci;
        cu = nu; ci = ni;
        nu = (float*)tu; ni = (float*)ti;
    }
}

// Round 4
// 1357.005 us; speedup vs baseline: 1.1248x; 1.0451x over previous
//
#include <hip/hip_runtime.h>

#define NU 100000
#define NI 100000
#define NE 500000
#define HD 128

using bf16x8 = __attribute__((ext_vector_type(8))) __bf16;
using f32x4  = __attribute__((ext_vector_type(4))) float;

// ---------------- src-degree histograms (3 arrays; dst degrees come from CSR cnt) ----
__global__ __launch_bounds__(256) void src_count(
    const int* __restrict__ s0, const int* __restrict__ s1,
    const int* __restrict__ s2, float* __restrict__ deg)
{
    long long t = (long long)blockIdx.x * 256 + threadIdx.x;
    if (t >= 3LL * NE) return;
    int a = (int)(t / NE);
    int e = (int)(t - (long long)a * NE);
    const int* p = (a == 0) ? s0 : (a == 1) ? s1 : s2;
    atomicAdd(&deg[a * 200000 + p[e]], 1.0f);
}

__global__ __launch_bounds__(256) void deg_finalize(float* __restrict__ deg)
{
    int t = blockIdx.x * 256 + threadIdx.x;
    if (t < 600000) deg[t] = rsqrtf(fmaxf(deg[t], 1.0f));
}

__global__ __launch_bounds__(256) void rs_from_cnt(const int* __restrict__ cnt,
                                                   float* __restrict__ rs, int n)
{
    int t = blockIdx.x * 256 + threadIdx.x;
    if (t < n) rs[t] = rsqrtf(fmaxf((float)cnt[t], 1.0f));
}

// ---------------- CSR build ----------------
__global__ __launch_bounds__(256) void count_dst(const int* __restrict__ dst,
                                                 int* __restrict__ cnt)
{
    int e = blockIdx.x * 256 + threadIdx.x;
    if (e < NE) atomicAdd(&cnt[dst[e]], 1);
}

__global__ __launch_bounds__(256) void scan_block(const int* __restrict__ cnt, int n,
                                                  int* __restrict__ rp,
                                                  int* __restrict__ bsum)
{
    __shared__ int s[256];
    int gid = blockIdx.x * 256 + threadIdx.x;
    int v = (gid < n) ? cnt[gid] : 0;
    s[threadIdx.x] = v;
    __syncthreads();
#pragma unroll
    for (int off = 1; off < 256; off <<= 1) {
        int t = (threadIdx.x >= off) ? s[threadIdx.x - off] : 0;
        __syncthreads();
        s[threadIdx.x] += t;
        __syncthreads();
    }
    if (gid < n) rp[gid] = s[threadIdx.x] - v;   // exclusive
    if (threadIdx.x == 255) bsum[blockIdx.x] = s[255];
}

__global__ __launch_bounds__(512) void scan_bsums(int* __restrict__ bsum, int nb)
{
    __shared__ int s[512];
    int v = (threadIdx.x < nb) ? bsum[threadIdx.x] : 0;
    s[threadIdx.x] = v;
    __syncthreads();
#pragma unroll
    for (int off = 1; off < 512; off <<= 1) {
        int t = (threadIdx.x >= off) ? s[threadIdx.x - off] : 0;
        __syncthreads();
        s[threadIdx.x] += t;
        __syncthreads();
    }
    if (threadIdx.x < nb) bsum[threadIdx.x] = s[threadIdx.x] - v;
    if (threadIdx.x == 0) bsum[nb] = s[nb - 1];  // total
}

__global__ __launch_bounds__(256) void scan_add(int* __restrict__ rp,
                                                const int* __restrict__ bsum,
                                                int n, int nb)
{
    int gid = blockIdx.x * 256 + threadIdx.x;
    if (gid < n) rp[gid] += bsum[blockIdx.x];
    if (gid == 0) rp[n] = bsum[nb];
}

__global__ __launch_bounds__(256) void csr_fill(const int* __restrict__ src,
                                                const int* __restrict__ dst,
                                                const int* __restrict__ rp,
                                                int* __restrict__ cursor,
                                                int* __restrict__ eidx)
{
    int e = blockIdx.x * 256 + threadIdx.x;
    if (e >= NE) return;
    int d = dst[e];
    int pos = rp[d] + atomicAdd(&cursor[d], 1);
    eidx[pos] = src[e];
}

// ---------------- W pre-pass: fp32 [K x 128] -> transposed bf16 hi/lo [128 x Kpad] ----
__global__ __launch_bounds__(256) void convert_w(
    const float* __restrict__ W, int K, int Kpad,
    __bf16* __restrict__ Wh, __bf16* __restrict__ Wl)
{
    int t = blockIdx.x * 256 + threadIdx.x;
    if (t >= 128 * Kpad) return;
    int k = t >> 7;
    int n = t & 127;
    float x = (k < K) ? W[k * 128 + n] : 0.f;
    __bf16 h = (__bf16)x;
    float r = x - (float)h;
    Wh[n * Kpad + k] = h;
    Wl[n * Kpad + k] = (__bf16)r;
}

// ---------------- fused layer kernel helpers ----------------

// gather one 32-row tile: 32 groups x 8 lanes; group g owns row r0+g;
// lane gl owns cols gl*16..gl*16+15. fp32 accumulate -> bf16 hi/lo -> LDS.
// MLP: 4 edges in flight (contiguous ei loads), 4 float4 row-loads per edge per lane.
__device__ __forceinline__ void gather_stage(
    const float* __restrict__ X, const int* __restrict__ rp,
    const int* __restrict__ ei, const float* __restrict__ rs,
    int r0, int M, int g, int gl, __bf16* sAh, __bf16* sAl)
{
    const int row = r0 + g;
    float a[16];
#pragma unroll
    for (int q = 0; q < 16; ++q) a[q] = 0.f;

    if (row < M) {
        const int beg = rp[row], end = rp[row + 1];
        const long long coff = (long long)gl * 16;
        int p = beg;
        for (; p + 4 <= end; p += 4) {
            int s0 = ei[p], s1 = ei[p + 1], s2 = ei[p + 2], s3 = ei[p + 3];
            float w0 = rs[s0], w1 = rs[s1], w2 = rs[s2], w3 = rs[s3];
            const float* x0 = X + (long long)s0 * HD + coff;
            const float* x1 = X + (long long)s1 * HD + coff;
            const float* x2 = X + (long long)s2 * HD + coff;
            const float* x3 = X + (long long)s3 * HD + coff;
            float4 v0[4], v1[4], v2[4], v3[4];
#pragma unroll
            for (int r = 0; r < 4; ++r) v0[r] = *(const float4*)(x0 + r * 4);
#pragma unroll
            for (int r = 0; r < 4; ++r) v1[r] = *(const float4*)(x1 + r * 4);
#pragma unroll
            for (int r = 0; r < 4; ++r) v2[r] = *(const float4*)(x2 + r * 4);
#pragma unroll
            for (int r = 0; r < 4; ++r) v3[r] = *(const float4*)(x3 + r * 4);
#pragma unroll
            for (int r = 0; r < 4; ++r) {
                a[r * 4 + 0] = fmaf(v0[r].x, w0, a[r * 4 + 0]);
                a[r * 4 + 1] = fmaf(v0[r].y, w0, a[r * 4 + 1]);
                a[r * 4 + 2] = fmaf(v0[r].z, w0, a[r * 4 + 2]);
                a[r * 4 + 3] = fmaf(v0[r].w, w0, a[r * 4 + 3]);
            }
#pragma unroll
            for (int r = 0; r < 4; ++r) {
                a[r * 4 + 0] = fmaf(v1[r].x, w1, a[r * 4 + 0]);
                a[r * 4 + 1] = fmaf(v1[r].y, w1, a[r * 4 + 1]);
                a[r * 4 + 2] = fmaf(v1[r].z, w1, a[r * 4 + 2]);
                a[r * 4 + 3] = fmaf(v1[r].w, w1, a[r * 4 + 3]);
            }
#pragma unroll
            for (int r = 0; r < 4; ++r) {
                a[r * 4 + 0] = fmaf(v2[r].x, w2, a[r * 4 + 0]);
                a[r * 4 + 1] = fmaf(v2[r].y, w2, a[r * 4 + 1]);
                a[r * 4 + 2] = fmaf(v2[r].z, w2, a[r * 4 + 2]);
                a[r * 4 + 3] = fmaf(v2[r].w, w2, a[r * 4 + 3]);
            }
#pragma unroll
            for (int r = 0; r < 4; ++r) {
                a[r * 4 + 0] = fmaf(v3[r].x, w3, a[r * 4 + 0]);
                a[r * 4 + 1] = fmaf(v3[r].y, w3, a[r * 4 + 1]);
                a[r * 4 + 2] = fmaf(v3[r].z, w3, a[r * 4 + 2]);
                a[r * 4 + 3] = fmaf(v3[r].w, w3, a[r * 4 + 3]);
            }
        }
        if (p + 2 <= end) {
            int s0 = ei[p], s1 = ei[p + 1];
            float w0 = rs[s0], w1 = rs[s1];
            const float* x0 = X + (long long)s0 * HD + coff;
            const float* x1 = X + (long long)s1 * HD + coff;
            float4 v0[4], v1[4];
#pragma unroll
            for (int r = 0; r < 4; ++r) v0[r] = *(const float4*)(x0 + r * 4);
#pragma unroll
            for (int r = 0; r < 4; ++r) v1[r] = *(const float4*)(x1 + r * 4);
#pragma unroll
            for (int r = 0; r < 4; ++r) {
                a[r * 4 + 0] = fmaf(v0[r].x, w0, a[r * 4 + 0]);
                a[r * 4 + 1] = fmaf(v0[r].y, w0, a[r * 4 + 1]);
                a[r * 4 + 2] = fmaf(v0[r].z, w0, a[r * 4 + 2]);
                a[r * 4 + 3] = fmaf(v0[r].w, w0, a[r * 4 + 3]);
            }
#pragma unroll
            for (int r = 0; r < 4; ++r) {
                a[r * 4 + 0] = fmaf(v1[r].x, w1, a[r * 4 + 0]);
                a[r * 4 + 1] = fmaf(v1[r].y, w1, a[r * 4 + 1]);
                a[r * 4 + 2] = fmaf(v1[r].z, w1, a[r * 4 + 2]);
                a[r * 4 + 3] = fmaf(v1[r].w, w1, a[r * 4 + 3]);
            }
            p += 2;
        }
        if (p < end) {
            int s0 = ei[p];
            float w0 = rs[s0];
            const float* x0 = X + (long long)s0 * HD + coff;
            float4 v0[4];
#pragma unroll
            for (int r = 0; r < 4; ++r) v0[r] = *(const float4*)(x0 + r * 4);
#pragma unroll
            for (int r = 0; r < 4; ++r) {
                a[r * 4 + 0] = fmaf(v0[r].x, w0, a[r * 4 + 0]);
                a[r * 4 + 1] = fmaf(v0[r].y, w0, a[r * 4 + 1]);
                a[r * 4 + 2] = fmaf(v0[r].z, w0, a[r * 4 + 2]);
                a[r * 4 + 3] = fmaf(v0[r].w, w0, a[r * 4 + 3]);
            }
        }
    }

    bf16x8 h0, h1, l0, l1;
#pragma unroll
    for (int q = 0; q < 8; ++q) {
        __bf16 hq = (__bf16)a[q];
        h0[q] = hq;
        l0[q] = (__bf16)(a[q] - (float)hq);
    }
#pragma unroll
    for (int q = 0; q < 8; ++q) {
        __bf16 hq = (__bf16)a[8 + q];
        h1[q] = hq;
        l1[q] = (__bf16)(a[8 + q] - (float)hq);
    }
    *(bf16x8*)(&sAh[g * 136 + gl * 16])     = h0;
    *(bf16x8*)(&sAh[g * 136 + gl * 16 + 8]) = h1;
    *(bf16x8*)(&sAl[g * 136 + gl * 16])     = l0;
    *(bf16x8*)(&sAl[g * 136 + gl * 16 + 8]) = l1;
}

// W fragments for this wave's 32 cols, all K=128, hi+lo (64 VGPRs); L2-resident source.
__device__ __forceinline__ void load_wfrags(const __bf16* __restrict__ W,
                                            int wv, int lr, int lq,
                                            bf16x8 bh[2][4], bf16x8 bl[2][4])
{
    const __bf16* Wlo = W + 16384;
#pragma unroll
    for (int j = 0; j < 2; ++j)
#pragma unroll
        for (int kc = 0; kc < 4; ++kc) {
            int col = wv * 32 + j * 16 + lr;
            int k = kc * 32 + lq * 8;
            bh[j][kc] = *(const bf16x8*)(W + col * 128 + k);
            bl[j][kc] = *(const bf16x8*)(Wlo + col * 128 + k);
        }
}

__device__ __forceinline__ void mfma_tile(const __bf16* sAh, const __bf16* sAl,
                                          int lr, int lq,
                                          const bf16x8 bh[2][4], const bf16x8 bl[2][4],
                                          f32x4 acc[2][2])
{
#pragma unroll
    for (int i = 0; i < 2; ++i)
#pragma unroll
        for (int kc = 0; kc < 4; ++kc) {
            bf16x8 ah = *(const bf16x8*)(&sAh[(i * 16 + lr) * 136 + kc * 32 + lq * 8]);
            bf16x8 al = *(const bf16x8*)(&sAl[(i * 16 + lr) * 136 + kc * 32 + lq * 8]);
#pragma unroll
            for (int j = 0; j < 2; ++j) {
                acc[i][j] = __builtin_amdgcn_mfma_f32_16x16x32_bf16(ah, bh[j][kc], acc[i][j], 0, 0, 0);
                acc[i][j] = __builtin_amdgcn_mfma_f32_16x16x32_bf16(ah, bl[j][kc], acc[i][j], 0, 0, 0);
                acc[i][j] = __builtin_amdgcn_mfma_f32_16x16x32_bf16(al, bh[j][kc], acc[i][j], 0, 0, 0);
            }
        }
}

// ---------------- fused layer: gather + split-bf16 GEMM + (optional) 2nd edge set ----
// C[row] = relu(gatherA@Wa * rsa_d + ba) [+ relu(gatherB@Wb * rsb_d + bb)]
// One 32-row output tile per block; output written exactly once (no accum RMW).
__global__ __launch_bounds__(256) void layer_fused(
    const float* __restrict__ Xa, const float* __restrict__ Xb,   // Xb==null -> single set
    const int* __restrict__ rp_a, const int* __restrict__ ei_a,
    const float* __restrict__ rsa_s, const float* __restrict__ rsa_d,
    const __bf16* __restrict__ Wa, const float* __restrict__ ba,
    const int* __restrict__ rp_b, const int* __restrict__ ei_b,
    const float* __restrict__ rsb_s, const float* __restrict__ rsb_d,
    const __bf16* __restrict__ Wb, const float* __restrict__ bb,
    int do_relu, int M, float* __restrict__ C)
{
    __shared__ __bf16 sAh[32 * 136];
    __shared__ __bf16 sAl[32 * 136];

    const int tid  = threadIdx.x;
    const int lane = tid & 63;
    const int wv   = tid >> 6;       // wave -> 32-col slice
    const int lr   = lane & 15;
    const int lq   = lane >> 4;
    const int g    = tid >> 3;       // gather group 0..31 (one row each)
    const int gl   = tid & 7;        // lane in group (16 cols each)
    const int r0   = blockIdx.x * 32;
    const bool dual = (Xb != nullptr);

    bf16x8 bh[2][4], bl[2][4];
    f32x4 accA[2][2], accB[2][2];
#pragma unroll
    for (int i = 0; i < 2; ++i)
#pragma unroll
        for (int j = 0; j < 2; ++j)
#pragma unroll
            for (int t = 0; t < 4; ++t) { accA[i][j][t] = 0.f; accB[i][j][t] = 0.f; }

    // ---- set A ---- (W-frag loads AFTER gather: keeps gather-phase VGPRs low)
    gather_stage(Xa, rp_a, ei_a, rsa_s, r0, M, g, gl, sAh, sAl);
    load_wfrags(Wa, wv, lr, lq, bh, bl);
    __syncthreads();                       // tile staged
    mfma_tile(sAh, sAl, lr, lq, bh, bl, accA);

    if (dual) {
        __syncthreads();                   // all reads of tile A complete
        gather_stage(Xb, rp_b, ei_b, rsb_s, r0, M, g, gl, sAh, sAl);
        load_wfrags(Wb, wv, lr, lq, bh, bl);
        __syncthreads();
        mfma_tile(sAh, sAl, lr, lq, bh, bl, accB);
    }

    // ---- epilogue: per-set scale+bias+relu, sum, single write ----
#pragma unroll
    for (int j = 0; j < 2; ++j) {
        const int col = wv * 32 + j * 16 + lr;
        const float bva = ba[col];
        const float bvb = dual ? bb[col] : 0.f;
#pragma unroll
        for (int i = 0; i < 2; ++i) {
            const int rbase = r0 + i * 16 + lq * 4;
#pragma unroll
            for (int t = 0; t < 4; ++t) {
                const int row = rbase + t;
                if (row < M) {
                    float ya = accA[i][j][t] * rsa_d[row] + bva;
                    if (do_relu) ya = fmaxf(ya, 0.f);
                    float out = ya;
                    if (dual) {
                        float yb = accB[i][j][t] * rsb_d[row] + bvb;
                        if (do_relu) yb = fmaxf(yb, 0.f);
                        out += yb;
                    }
                    C[(long long)row * HD + col] = out;
                }
            }
        }
    }
}

// ---------------- generic-K MFMA GEMM (embeds only; unchanged control) ----------------
__global__ __launch_bounds__(256) void gemm128_mfma(
    const float* __restrict__ A, int K, int Kpad, int M,
    const __bf16* __restrict__ Wh, const __bf16* __restrict__ Wl,
    const float* __restrict__ bias,
    float* __restrict__ C)
{
    __shared__ __bf16 sAh[64 * 40];
    __shared__ __bf16 sAl[64 * 40];
    __shared__ __bf16 sWh[128 * 40];
    __shared__ __bf16 sWl[128 * 40];

    const int tid  = threadIdx.x;
    const int row0 = blockIdx.x * 64;
    const int lane = tid & 63;
    const int wv   = tid >> 6;
    const int lr   = lane & 15;
    const int lq   = lane >> 4;

    f32x4 acc[4][2];
#pragma unroll
    for (int i = 0; i < 4; ++i)
#pragma unroll
        for (int j = 0; j < 2; ++j)
#pragma unroll
            for (int t = 0; t < 4; ++t) acc[i][j][t] = 0.f;

    const int arow  = tid >> 2;
    const int akoff = (tid & 3) << 3;
    const int wcol  = tid >> 1;
    const int wkoff = (tid & 1) << 4;

    const int nk = Kpad >> 5;
    for (int kc = 0; kc < nk; ++kc) {
        const int k0 = kc << 5;
        {
            int row = row0 + arow;
            int k = k0 + akoff;
            float f[8];
            if (row < M && k + 7 < K) {
                float4 v0 = *(const float4*)(A + (long long)row * K + k);
                float4 v1 = *(const float4*)(A + (long long)row * K + k + 4);
                f[0] = v0.x; f[1] = v0.y; f[2] = v0.z; f[3] = v0.w;
                f[4] = v1.x; f[5] = v1.y; f[6] = v1.z; f[7] = v1.w;
            } else {
#pragma unroll
                for (int t = 0; t < 8; ++t)
                    f[t] = (row < M && k + t < K) ? A[(long long)row * K + k + t] : 0.f;
            }
            bf16x8 h8, l8;
#pragma unroll
            for (int t = 0; t < 8; ++t) {
                __bf16 h = (__bf16)f[t];
                h8[t] = h;
                l8[t] = (__bf16)(f[t] - (float)h);
            }
            *(bf16x8*)(&sAh[arow * 40 + akoff]) = h8;
            *(bf16x8*)(&sAl[arow * 40 + akoff]) = l8;
        }
        {
            const __bf16* ph = Wh + (long long)wcol * Kpad + k0 + wkoff;
            const __bf16* pl = Wl + (long long)wcol * Kpad + k0 + wkoff;
            bf16x8 w0 = *(const bf16x8*)(ph);
            bf16x8 w1 = *(const bf16x8*)(ph + 8);
            bf16x8 x0 = *(const bf16x8*)(pl);
            bf16x8 x1 = *(const bf16x8*)(pl + 8);
            *(bf16x8*)(&sWh[wcol * 40 + wkoff])     = w0;
            *(bf16x8*)(&sWh[wcol * 40 + wkoff + 8]) = w1;
            *(bf16x8*)(&sWl[wcol * 40 + wkoff])     = x0;
            *(bf16x8*)(&sWl[wcol * 40 + wkoff + 8]) = x1;
        }
        __syncthreads();
        bf16x8 bh[2], bl[2];
#pragma unroll
        for (int j = 0; j < 2; ++j) {
            int c = wv * 32 + j * 16 + lr;
            bh[j] = *(const bf16x8*)(&sWh[c * 40 + lq * 8]);
            bl[j] = *(const bf16x8*)(&sWl[c * 40 + lq * 8]);
        }
#pragma unroll
        for (int i = 0; i < 4; ++i) {
            bf16x8 ah = *(const bf16x8*)(&sAh[(i * 16 + lr) * 40 + lq * 8]);
            bf16x8 al = *(const bf16x8*)(&sAl[(i * 16 + lr) * 40 + lq * 8]);
#pragma unroll
            for (int j = 0; j < 2; ++j) {
                acc[i][j] = __builtin_amdgcn_mfma_f32_16x16x32_bf16(ah, bh[j], acc[i][j], 0, 0, 0);
                acc[i][j] = __builtin_amdgcn_mfma_f32_16x16x32_bf16(ah, bl[j], acc[i][j], 0, 0, 0);
                acc[i][j] = __builtin_amdgcn_mfma_f32_16x16x32_bf16(al, bh[j], acc[i][j], 0, 0, 0);
            }
        }
        __syncthreads();
    }

#pragma unroll
    for (int j = 0; j < 2; ++j) {
        int col = wv * 32 + j * 16 + lr;
        float bv = bias ? bias[col] : 0.f;
#pragma unroll
        for (int i = 0; i < 4; ++i) {
            int r0 = row0 + i * 16 + lq * 4;
#pragma unroll
            for (int t = 0; t < 4; ++t) {
                int row = r0 + t;
                if (row < M) {
                    float v = acc[i][j][t] + bv;
                    C[(long long)row * 128 + col] = v;
                }
            }
        }
    }
}

static inline void build_csr(const int* src, const int* dst, int n_dst,
                             int* cnt, int* rp, int* cursor, int* eidx,
                             int* bsum, float* rs_in, hipStream_t stream)
{
    const int nb = (n_dst + 255) / 256;
    hipMemsetAsync(cnt, 0, n_dst * sizeof(int), stream);
    count_dst<<<(NE + 255) / 256, 256, 0, stream>>>(dst, cnt);
    rs_from_cnt<<<nb, 256, 0, stream>>>(cnt, rs_in, n_dst);
    scan_block<<<nb, 256, 0, stream>>>(cnt, n_dst, rp, bsum);
    scan_bsums<<<1, 512, 0, stream>>>(bsum, nb);
    scan_add<<<nb, 256, 0, stream>>>(rp, bsum, n_dst, nb);
    hipMemsetAsync(cursor, 0, n_dst * sizeof(int), stream);
    csr_fill<<<(NE + 255) / 256, 256, 0, stream>>>(src, dst, rp, cursor, eidx);
}

extern "C" void kernel_launch(void* const* d_in, const int* in_sizes, int n_in,
                              void* d_out, int out_size, void* d_ws, size_t ws_size,
                              hipStream_t stream)
{
    const float* feat_user = (const float*)d_in[0];
    const float* feat_item = (const float*)d_in[1];
    const int* src_uu = (const int*)d_in[2];
    const int* dst_uu = (const int*)d_in[3];
    const int* src_ui = (const int*)d_in[4];
    const int* dst_ui = (const int*)d_in[5];
    const int* src_iu = (const int*)d_in[6];
    const int* dst_iu = (const int*)d_in[7];
    const float* We_u = (const float*)d_in[8];
    const float* be_u = (const float*)d_in[9];
    const float* We_i = (const float*)d_in[10];
    const float* be_i = (const float*)d_in[11];

    float* hu = (float*)d_out;                 // [NU x 128] final user out
    float* hi = hu + (size_t)NU * HD;          // [NI x 128] final item out

    float* ws = (float*)d_ws;
    float* wu = ws;                            // ping-pong state (user)
    float* wi = wu + (size_t)NU * HD;          // ping-pong state (item)
    float* deg = wi + (size_t)NI * HD;         // 6 x 100000
    float* rs_out_uu = deg + 0;
    float* rs_in_uu  = deg + 100000;
    float* rs_out_ui = deg + 200000;
    float* rs_in_ui  = deg + 300000;
    float* rs_out_iu = deg + 400000;
    float* rs_in_iu  = deg + 500000;

    int* ib = (int*)(deg + 600000);
    int* rp_uu   = ib;                 ib += 100001;
    int* rp_ui   = ib;                 ib += 100001;
    int* rp_iu   = ib;                 ib += 100001;
    int* ei_uu   = ib;                 ib += NE;
    int* ei_ui   = ib;                 ib += NE;
    int* ei_iu   = ib;                 ib += NE;
    int* cnt     = ib;                 ib += 100000;
    int* cursor  = ib;                 ib += 100000;
    int* bsum    = ib;                 ib += 1024;

    // bf16 hi/lo transposed weight buffers (~884 KB)
    uintptr_t wp = ((uintptr_t)ib + 63) & ~(uintptr_t)63;
    __bf16* wtbuf = (__bf16*)wp;
    __bf16* eu_h = wtbuf;                       // 128*256
    __bf16* eu_l = eu_h + 128 * 256;
    __bf16* ei_h = eu_l + 128 * 256;            // 128*320
    __bf16* ei_l = ei_h + 128 * 320;
    __bf16* lw   = ei_l + 128 * 320;            // 9 x (hi,lo) of 128*128

    // weight conversion pre-pass (tiny)
    convert_w<<<(128 * 256 + 255) / 256, 256, 0, stream>>>(We_u, 256, 256, eu_h, eu_l);
    convert_w<<<(128 * 320 + 255) / 256, 256, 0, stream>>>(We_i, 300, 320, ei_h, ei_l);
    for (int l = 0; l < 3; ++l)
        for (int e = 0; e < 3; ++e) {
            const float* W = (const float*)d_in[12 + 6 * l + 2 * e];
            __bf16* h = lw + (size_t)(l * 3 + e) * 2 * 16384;
            convert_w<<<64, 256, 0, stream>>>(W, 128, 128, h, h + 16384);
        }

    // src-degree histograms only (dst degrees derived from CSR counts)
    hipMemsetAsync(deg, 0, 600000 * sizeof(float), stream);
    src_count<<<(3 * NE + 255) / 256, 256, 0, stream>>>(src_uu, src_ui, src_iu, deg);
    deg_finalize<<<(600000 + 255) / 256, 256, 0, stream>>>(deg);

    // CSR (dst-major) per etype; each also produces rs_in_* from its histogram
    build_csr(src_uu, dst_uu, NU, cnt, rp_uu, cursor, ei_uu, bsum, rs_in_uu, stream);
    build_csr(src_ui, dst_ui, NI, cnt, rp_ui, cursor, ei_ui, bsum, rs_in_ui, stream);
    build_csr(src_iu, dst_iu, NU, cnt, rp_iu, cursor, ei_iu, bsum, rs_in_iu, stream);

    // HeteroLinear embed -> ping-pong buffers (ws)
    gemm128_mfma<<<(NU + 63) / 64, 256, 0, stream>>>(feat_user, 256, 256, NU,
                                                     eu_h, eu_l, be_u, wu);
    gemm128_mfma<<<(NI + 63) / 64, 256, 0, stream>>>(feat_item, 300, 320, NI,
                                                     ei_h, ei_l, be_i, wi);

    // layers: ping-pong ws <-> d_out; layer 2 lands in d_out
    const float* cu = wu; const float* ci = wi;
    float* nu = hu; float* ni = hi;
    const int blocks_u = (NU + 31) / 32;
    const int blocks_i = (NI + 31) / 32;
    for (int l = 0; l < 3; ++l) {
        const float* b_uu = (const float*)d_in[12 + 6 * l + 1];
        const float* b_ui = (const float*)d_in[12 + 6 * l + 3];
        const float* b_iu = (const float*)d_in[12 + 6 * l + 5];
        const __bf16* Wuu = lw + (size_t)(l * 3 + 0) * 2 * 16384;
        const __bf16* Wui = lw + (size_t)(l * 3 + 1) * 2 * 16384;
        const __bf16* Wiu = lw + (size_t)(l * 3 + 2) * 2 * 16384;
        const int relu = (l < 2) ? 1 : 0;

        // user dst: relu(gather_uu(cu)@Wuu) + relu(gather_iu(ci)@Wiu), single write
        layer_fused<<<blocks_u, 256, 0, stream>>>(
            cu, ci,
            rp_uu, ei_uu, rs_out_uu, rs_in_uu, Wuu, b_uu,
            rp_iu, ei_iu, rs_out_iu, rs_in_iu, Wiu, b_iu,
            relu, NU, nu);
        // item dst: relu(gather_ui(cu)@Wui), single write
        layer_fused<<<blocks_i, 256, 0, stream>>>(
            cu, nullptr,
            rp_ui, ei_ui, rs_out_ui, rs_in_ui, Wui, b_ui,
            rp_ui, ei_ui, rs_out_ui, rs_in_ui, Wui, b_ui,
            relu, NI, ni);

        // swap ping-pong
        const float* tu = cu; const float* ti = ci;
        cu = nu; ci = ni;
        nu = (float*)tu; ni = (float*)ti;
    }
}